// Round 4
// baseline (104.261 us; speedup 1.0000x reference)
//
#include <hip/hip_runtime.h>

#define H 128

typedef float f2 __attribute__((ext_vector_type(2)));

// ---------------------------------------------------------------------------
// Kernel 1: fused 3-layer MLP + Ws1 projection for agents AND regions.
//   agent blocks: pa[a][:] = relu(relu(xA@Wa1+ba1)@Wa2+ba2) @ Ws1[:128] + bs1
//   region blocks: pr[r][:] = relu(relu(xR@Wr1+br1)@Wr2+br2) @ Ws1[128:]
// Block = 256 threads = two independent 4-row groups (g = tid>>7), thread
// j = tid&127 owns output column j of its group's rows. 256 blocks = 1/CU.
// NOTE: deliberately NOT raising block count further — each block re-reads
// W2+W3 (128 KB); 256 blocks = 36 MB aggregate L2 traffic ~= the VALU time;
// 512 blocks would double it and become L2-bound.
// ---------------------------------------------------------------------------
__global__ __launch_bounds__(256) void emb_kernel(
    const float* __restrict__ xA, const float* __restrict__ xR,
    const float* __restrict__ Wa1, const float* __restrict__ ba1,
    const float* __restrict__ Wa2, const float* __restrict__ ba2,
    const float* __restrict__ Wr1, const float* __restrict__ br1,
    const float* __restrict__ Wr2, const float* __restrict__ br2,
    const float* __restrict__ Ws1, const float* __restrict__ bs1,
    float* __restrict__ pa, float* __restrict__ pr,
    int na, int nr)
{
    const int ROWS = 8;                 // per block; 4 per half-block group
    const int b = blockIdx.x;
    const int nblkA = na / ROWS;
    const bool isA = (b < nblkA);                 // wave-uniform branch
    const int row0 = (isA ? b : b - nblkA) * ROWS;
    const float* __restrict__ x  = isA ? xA : xR;
    const float* __restrict__ W1 = isA ? Wa1 : Wr1;
    const float* __restrict__ b1 = isA ? ba1 : br1;
    const float* __restrict__ W2 = isA ? Wa2 : Wr2;
    const float* __restrict__ b2 = isA ? ba2 : br2;
    const float* __restrict__ W3 = isA ? Ws1 : Ws1 + H * H; // Ws1_a / Ws1_r
    float* __restrict__ outp     = isA ? pa : pr;
    const int in_dim = isA ? 24 : 20;

    __shared__ __align__(16) float sX[ROWS][24];   // row stride 96 B
    __shared__ __align__(16) float sH[ROWS][H];

    const int tid = threadIdx.x;
    const int j = tid & 127;            // output column
    const int g = tid >> 7;             // row group: rows g*4 .. g*4+3
    const int r0g = g * 4;

    // stage x rows (zero-pad columns >= in_dim so a fixed-24 unroll is safe)
    {
        int idx = tid;                  // 0..255, need 0..191
        if (idx < ROWS * 24) {
            int r = idx / 24, k = idx - r * 24;
            sX[r][k] = (k < in_dim) ? x[(row0 + r) * in_dim + k] : 0.f;
        }
    }
    __syncthreads();

    // ---- layer 1: h1 = relu(x @ W1 + b1), 4 rows per thread ----
    float w1[24];
    #pragma unroll
    for (int k = 0; k < 24; ++k)
        w1[k] = (k < in_dim) ? W1[k * H + j] : 0.f;   // predicated, no OOB
    {
        const float bj = b1[j];
        #pragma unroll
        for (int r = 0; r < 4; ++r) {
            const float4* sx4 = (const float4*)&sX[r0g + r][0];
            float s = bj;
            #pragma unroll
            for (int k4 = 0; k4 < 6; ++k4) {
                float4 xv = sx4[k4];
                s += xv.x * w1[k4 * 4 + 0];
                s += xv.y * w1[k4 * 4 + 1];
                s += xv.z * w1[k4 * 4 + 2];
                s += xv.w * w1[k4 * 4 + 3];
            }
            sH[r0g + r][j] = fmaxf(s, 0.f);
        }
    }
    __syncthreads();

    float acc[4];
    // ---- layer 2: h2 = relu(h1 @ W2 + b2) ----
    {
        const float bj = b2[j];
        #pragma unroll
        for (int r = 0; r < 4; ++r) acc[r] = bj;
    }
    #pragma unroll
    for (int kc = 0; kc < H; kc += 32) {
        float w2[32];
        #pragma unroll
        for (int kk = 0; kk < 32; ++kk) w2[kk] = W2[(kc + kk) * H + j];
        #pragma unroll
        for (int r = 0; r < 4; ++r) {
            const float4* sh4 = (const float4*)&sH[r0g + r][kc];
            float s = acc[r];
            #pragma unroll
            for (int k4 = 0; k4 < 8; ++k4) {
                float4 hv = sh4[k4];
                s += hv.x * w2[k4 * 4 + 0];
                s += hv.y * w2[k4 * 4 + 1];
                s += hv.z * w2[k4 * 4 + 2];
                s += hv.w * w2[k4 * 4 + 3];
            }
            acc[r] = s;
        }
    }
    __syncthreads();
    #pragma unroll
    for (int r = 0; r < 4; ++r) sH[r0g + r][j] = fmaxf(acc[r], 0.f);
    __syncthreads();

    // ---- layer 3 (projection): p = h2 @ W3 (+ bs1 on agent side) ----
    {
        const float init = isA ? bs1[j] : 0.f;
        #pragma unroll
        for (int r = 0; r < 4; ++r) acc[r] = init;
    }
    #pragma unroll
    for (int kc = 0; kc < H; kc += 32) {
        float w3[32];
        #pragma unroll
        for (int kk = 0; kk < 32; ++kk) w3[kk] = W3[(kc + kk) * H + j];
        #pragma unroll
        for (int r = 0; r < 4; ++r) {
            const float4* sh4 = (const float4*)&sH[r0g + r][kc];
            float s = acc[r];
            #pragma unroll
            for (int k4 = 0; k4 < 8; ++k4) {
                float4 hv = sh4[k4];
                s += hv.x * w3[k4 * 4 + 0];
                s += hv.y * w3[k4 * 4 + 1];
                s += hv.z * w3[k4 * 4 + 2];
                s += hv.w * w3[k4 * 4 + 3];
            }
            acc[r] = s;
        }
    }
    #pragma unroll
    for (int r = 0; r < 4; ++r) outp[(row0 + r0g + r) * H + j] = acc[r];
}

// ---------------------------------------------------------------------------
// Kernel 2: scores[a][r] = sum_h relu(pa[a][h] + pr[r][h]) * Ws2[h] + bs2
// 64A x 16B tile / 256-thread block; micro-tile 4x1 per thread.
// Grid 64x16 = 1024 blocks = 4 blocks/CU = 16 waves/CU = 4 waves/SIMD
// (R3 ran 2 waves/SIMD; this halves exposed L1/LDS latency per wave).
// Pipe balance per CU per h4-step: LDS 16 waves x 1 ds_read_b128 x 12 cyc
// = 192 cyc == VALU 4 waves/SIMD x 24 pk-instr x 2 cyc = 192 cyc.
// A-fragments from global/L1 (address depends only on ty -> 4 unique 16B
// lines per instr, broadcast to 16 lanes; block A-slice 32 KB, L1-resident).
// B in LDS, XOR-swizzled: 16 lanes hit 8 offset groups x 4 banks = all 32
// banks, 2 lanes each = free (m136). LDS = 8 KB.
// ---------------------------------------------------------------------------
__global__ __launch_bounds__(256) void pair_kernel(
    const float* __restrict__ pa, const float* __restrict__ pr,
    const float* __restrict__ Ws2, const float* __restrict__ bs2,
    float* __restrict__ out, int nr)
{
    __shared__ float sB[16 * H];        // 8 KB

    const int tid = threadIdx.x;
    const int a0 = blockIdx.y * 64;
    const int r0 = blockIdx.x * 16;

    const float4* pr4 = (const float4*)pr;
    #pragma unroll
    for (int i = 0; i < 2; ++i) {
        int idx = i * 256 + tid;          // 0..511
        int row = idx >> 5;               // 0..15
        int c4  = idx & 31;               // float4 group 0..31
        int p   = (c4 ^ (row & 7)) << 2;  // swizzled float offset
        *(float4*)&sB[row * H + p] = pr4[(r0 + row) * (H / 4) + c4];
    }
    __syncthreads();

    const int tx = tid & 15;   // r dimension 0..15
    const int ty = tid >> 4;   // a dimension 0..15
    const int sw7 = tx & 7;    // thread-constant part of the B swizzle

    const float4* pa4 = (const float4*)pa;
    long aBase[4];             // float4 index of row (a0+ty*4+i)
    #pragma unroll
    for (int i = 0; i < 4; ++i) aBase[i] = (long)(a0 + ty * 4 + i) * (H / 4);
    const int bBase = tx * H;  // float index of row tx in sB

    f2 acc[4];
    #pragma unroll
    for (int i = 0; i < 4; ++i) acc[i] = (f2){0.f, 0.f};

    const float4* w4 = (const float4*)Ws2;   // wave-uniform -> s_load
    const f2 zero = {0.f, 0.f};

    #pragma unroll 8
    for (int h4 = 0; h4 < H / 4; ++h4) {
        float4 wv = w4[h4];
        f2 wlo = {wv.x, wv.y}, whi = {wv.z, wv.w};
        const int sw = (h4 ^ sw7) << 2;       // B swizzle offset this step
        float4 av[4];
        #pragma unroll
        for (int i = 0; i < 4; ++i)
            av[i] = pa4[aBase[i] + h4];       // global, L1 broadcast
        float4 bv = *(const float4*)&sB[bBase + sw];
        f2 blo = {bv.x, bv.y}, bhi = {bv.z, bv.w};
        #pragma unroll
        for (int i = 0; i < 4; ++i) {
            f2 alo = {av[i].x, av[i].y}, ahi = {av[i].z, av[i].w};
            f2 zlo = __builtin_elementwise_max(alo + blo, zero);
            f2 zhi = __builtin_elementwise_max(ahi + bhi, zero);
            acc[i] += zlo * wlo;   // -> v_pk_fma_f32
            acc[i] += zhi * whi;
        }
    }

    const float b2v = bs2[0];
    #pragma unroll
    for (int i = 0; i < 4; ++i) {
        int a = a0 + ty * 4 + i;
        out[(long)a * nr + (r0 + tx)] = acc[i].x + acc[i].y + b2v;
    }
}

extern "C" void kernel_launch(void* const* d_in, const int* in_sizes, int n_in,
                              void* d_out, int out_size, void* d_ws, size_t ws_size,
                              hipStream_t stream) {
    const float* xA  = (const float*)d_in[0];
    const float* xR  = (const float*)d_in[1];
    const float* Wa1 = (const float*)d_in[2];
    const float* ba1 = (const float*)d_in[3];
    const float* Wa2 = (const float*)d_in[4];
    const float* ba2 = (const float*)d_in[5];
    const float* Wr1 = (const float*)d_in[6];
    const float* br1 = (const float*)d_in[7];
    const float* Wr2 = (const float*)d_in[8];
    const float* br2 = (const float*)d_in[9];
    const float* Ws1 = (const float*)d_in[10];
    const float* bs1 = (const float*)d_in[11];
    const float* Ws2 = (const float*)d_in[12];
    const float* bs2 = (const float*)d_in[13];
    float* out = (float*)d_out;

    const int na = in_sizes[0] / 24;   // 1024
    const int nr = in_sizes[1] / 20;   // 1024

    float* pa = (float*)d_ws;                       // na*128 floats (bs1 folded in)
    float* pr = pa + (size_t)na * H;                // nr*128 floats

    emb_kernel<<<dim3(na / 8 + nr / 8), 256, 0, stream>>>(
        xA, xR, Wa1, ba1, Wa2, ba2, Wr1, br1, Wr2, br2, Ws1, bs1, pa, pr, na, nr);

    pair_kernel<<<dim3(nr / 16, na / 64), 256, 0, stream>>>(
        pa, pr, Ws2, bs2, out, nr);
}

// Round 5
// 101.820 us; speedup vs baseline: 1.0240x; 1.0240x over previous
//
#include <hip/hip_runtime.h>

#define H 128

typedef float f2 __attribute__((ext_vector_type(2)));

// ---------------------------------------------------------------------------
// Kernel 1: fused 3-layer MLP + Ws1 projection for agents AND regions.
//   agent blocks: pa[a][:] = relu(relu(xA@Wa1+ba1)@Wa2+ba2) @ Ws1[:128] + bs1
//   region blocks: pr[r][:] = relu(relu(xR@Wr1+br1)@Wr2+br2) @ Ws1[128:]
// Block = 256 threads = two independent 4-row groups (g = tid>>7), thread
// j = tid&127 owns output column j of its group's rows. 256 blocks = 1/CU.
// NOTE: NOT raising block count — each block re-reads W2+W3 (128 KB);
// 256 blocks = 36 MB aggregate L2 traffic ~= the VALU time; more blocks
// would double weight re-fetch and become L2-bound.
// ---------------------------------------------------------------------------
__global__ __launch_bounds__(256) void emb_kernel(
    const float* __restrict__ xA, const float* __restrict__ xR,
    const float* __restrict__ Wa1, const float* __restrict__ ba1,
    const float* __restrict__ Wa2, const float* __restrict__ ba2,
    const float* __restrict__ Wr1, const float* __restrict__ br1,
    const float* __restrict__ Wr2, const float* __restrict__ br2,
    const float* __restrict__ Ws1, const float* __restrict__ bs1,
    float* __restrict__ pa, float* __restrict__ pr,
    int na, int nr)
{
    const int ROWS = 8;                 // per block; 4 per half-block group
    const int b = blockIdx.x;
    const int nblkA = na / ROWS;
    const bool isA = (b < nblkA);                 // wave-uniform branch
    const int row0 = (isA ? b : b - nblkA) * ROWS;
    const float* __restrict__ x  = isA ? xA : xR;
    const float* __restrict__ W1 = isA ? Wa1 : Wr1;
    const float* __restrict__ b1 = isA ? ba1 : br1;
    const float* __restrict__ W2 = isA ? Wa2 : Wr2;
    const float* __restrict__ b2 = isA ? ba2 : br2;
    const float* __restrict__ W3 = isA ? Ws1 : Ws1 + H * H; // Ws1_a / Ws1_r
    float* __restrict__ outp     = isA ? pa : pr;
    const int in_dim = isA ? 24 : 20;

    __shared__ __align__(16) float sX[ROWS][24];   // row stride 96 B
    __shared__ __align__(16) float sH[ROWS][H];

    const int tid = threadIdx.x;
    const int j = tid & 127;            // output column
    const int g = tid >> 7;             // row group: rows g*4 .. g*4+3
    const int r0g = g * 4;

    // stage x rows (zero-pad columns >= in_dim so a fixed-24 unroll is safe)
    {
        int idx = tid;                  // 0..255, need 0..191
        if (idx < ROWS * 24) {
            int r = idx / 24, k = idx - r * 24;
            sX[r][k] = (k < in_dim) ? x[(row0 + r) * in_dim + k] : 0.f;
        }
    }
    __syncthreads();

    // ---- layer 1: h1 = relu(x @ W1 + b1), 4 rows per thread ----
    float w1[24];
    #pragma unroll
    for (int k = 0; k < 24; ++k)
        w1[k] = (k < in_dim) ? W1[k * H + j] : 0.f;   // predicated, no OOB
    {
        const float bj = b1[j];
        #pragma unroll
        for (int r = 0; r < 4; ++r) {
            const float4* sx4 = (const float4*)&sX[r0g + r][0];
            float s = bj;
            #pragma unroll
            for (int k4 = 0; k4 < 6; ++k4) {
                float4 xv = sx4[k4];
                s += xv.x * w1[k4 * 4 + 0];
                s += xv.y * w1[k4 * 4 + 1];
                s += xv.z * w1[k4 * 4 + 2];
                s += xv.w * w1[k4 * 4 + 3];
            }
            sH[r0g + r][j] = fmaxf(s, 0.f);
        }
    }
    __syncthreads();

    float acc[4];
    // ---- layer 2: h2 = relu(h1 @ W2 + b2) ----
    {
        const float bj = b2[j];
        #pragma unroll
        for (int r = 0; r < 4; ++r) acc[r] = bj;
    }
    #pragma unroll
    for (int kc = 0; kc < H; kc += 32) {
        float w2[32];
        #pragma unroll
        for (int kk = 0; kk < 32; ++kk) w2[kk] = W2[(kc + kk) * H + j];
        #pragma unroll
        for (int r = 0; r < 4; ++r) {
            const float4* sh4 = (const float4*)&sH[r0g + r][kc];
            float s = acc[r];
            #pragma unroll
            for (int k4 = 0; k4 < 8; ++k4) {
                float4 hv = sh4[k4];
                s += hv.x * w2[k4 * 4 + 0];
                s += hv.y * w2[k4 * 4 + 1];
                s += hv.z * w2[k4 * 4 + 2];
                s += hv.w * w2[k4 * 4 + 3];
            }
            acc[r] = s;
        }
    }
    __syncthreads();
    #pragma unroll
    for (int r = 0; r < 4; ++r) sH[r0g + r][j] = fmaxf(acc[r], 0.f);
    __syncthreads();

    // ---- layer 3 (projection): p = h2 @ W3 (+ bs1 on agent side) ----
    {
        const float init = isA ? bs1[j] : 0.f;
        #pragma unroll
        for (int r = 0; r < 4; ++r) acc[r] = init;
    }
    #pragma unroll
    for (int kc = 0; kc < H; kc += 32) {
        float w3[32];
        #pragma unroll
        for (int kk = 0; kk < 32; ++kk) w3[kk] = W3[(kc + kk) * H + j];
        #pragma unroll
        for (int r = 0; r < 4; ++r) {
            const float4* sh4 = (const float4*)&sH[r0g + r][kc];
            float s = acc[r];
            #pragma unroll
            for (int k4 = 0; k4 < 8; ++k4) {
                float4 hv = sh4[k4];
                s += hv.x * w3[k4 * 4 + 0];
                s += hv.y * w3[k4 * 4 + 1];
                s += hv.z * w3[k4 * 4 + 2];
                s += hv.w * w3[k4 * 4 + 3];
            }
            acc[r] = s;
        }
    }
    #pragma unroll
    for (int r = 0; r < 4; ++r) outp[(row0 + r0g + r) * H + j] = acc[r];
}

// ---------------------------------------------------------------------------
// Kernel 2: scores[a][r] = sum_h relu(pa[a][h] + pr[r][h]) * Ws2[h] + bs2
// 64A x 32B tile / 256-thread block; micro-tile 4x2 per thread.
// Grid 32x16 = 512 blocks = 2 blocks/CU = 8 waves/CU = 2 waves/SIMD.
// BEST-MEASURED CONFIG (R3: 101.4 us). R4's 64x16/1024-block variant
// regressed +2.8 us: per-block fixed overhead (prologue, staging barrier
// drain, epilogue) is ~25-30% of block lifetime at 32 K-iters; doubling
// block count doubles that overhead. Do not shrink tiles further.
// Pipe balance per CU per h4-step: LDS 8 waves x 2 ds_read_b128 x 12 cyc
// = 192 cyc == VALU 2 waves/SIMD x 48 pk-instr x 2 cyc = 192 cyc.
// A-fragments from global/L1: per-wave address spans only 4 rows -> 4
// unique 16B lines per instr, broadcast to 16 lanes; A-slice L1-resident.
// B in LDS, XOR-swizzled -> 2-way bank aliasing = free (m136). LDS = 16 KB.
// ---------------------------------------------------------------------------
__global__ __launch_bounds__(256) void pair_kernel(
    const float* __restrict__ pa, const float* __restrict__ pr,
    const float* __restrict__ Ws2, const float* __restrict__ bs2,
    float* __restrict__ out, int nr)
{
    __shared__ float sB[32 * H];        // 16 KB

    const int tid = threadIdx.x;
    const int a0 = blockIdx.y * 64;
    const int r0 = blockIdx.x * 32;

    const float4* pr4 = (const float4*)pr;
    #pragma unroll
    for (int i = 0; i < 4; ++i) {
        int idx = i * 256 + tid;          // 0..1023
        int row = idx >> 5;               // 0..31
        int c4  = idx & 31;               // float4 group 0..31
        int p   = (c4 ^ (row & 7)) << 2;  // swizzled float offset
        *(float4*)&sB[row * H + p] = pr4[(r0 + row) * (H / 4) + c4];
    }
    __syncthreads();

    const int tx = tid & 15;   // r dimension (16-wide: keeps swizzle 2-way)
    const int ty = tid >> 4;   // a dimension 0..15
    const int sw7 = tx & 7;    // thread-constant part of the B swizzle

    const float4* pa4 = (const float4*)pa;
    long aBase[4];             // float4 index of row (a0+ty*4+i)
    #pragma unroll
    for (int i = 0; i < 4; ++i) aBase[i] = (long)(a0 + ty * 4 + i) * (H / 4);
    int bBase[2];              // float index of row (tx+16j) in sB
    #pragma unroll
    for (int j = 0; j < 2; ++j) bBase[j] = (tx + 16 * j) * H;

    f2 acc[4][2];
    #pragma unroll
    for (int i = 0; i < 4; ++i)
        #pragma unroll
        for (int j = 0; j < 2; ++j) acc[i][j] = (f2){0.f, 0.f};

    const float4* w4 = (const float4*)Ws2;   // wave-uniform -> s_load
    const f2 zero = {0.f, 0.f};

    #pragma unroll 8
    for (int h4 = 0; h4 < H / 4; ++h4) {
        float4 wv = w4[h4];
        f2 wlo = {wv.x, wv.y}, whi = {wv.z, wv.w};
        const int sw = (h4 ^ sw7) << 2;       // B swizzle offset this step
        float4 av[4], bv[2];
        #pragma unroll
        for (int i = 0; i < 4; ++i)
            av[i] = pa4[aBase[i] + h4];       // global, L1 broadcast
        #pragma unroll
        for (int j = 0; j < 2; ++j)
            bv[j] = *(const float4*)&sB[bBase[j] + sw];
        #pragma unroll
        for (int i = 0; i < 4; ++i) {
            f2 alo = {av[i].x, av[i].y}, ahi = {av[i].z, av[i].w};
            #pragma unroll
            for (int j = 0; j < 2; ++j) {
                f2 blo = {bv[j].x, bv[j].y}, bhi = {bv[j].z, bv[j].w};
                f2 zlo = __builtin_elementwise_max(alo + blo, zero);
                f2 zhi = __builtin_elementwise_max(ahi + bhi, zero);
                acc[i][j] += zlo * wlo;   // -> v_pk_fma_f32
                acc[i][j] += zhi * whi;
            }
        }
    }

    const float b2v = bs2[0];
    #pragma unroll
    for (int i = 0; i < 4; ++i) {
        int a = a0 + ty * 4 + i;
        #pragma unroll
        for (int j = 0; j < 2; ++j) {
            out[(long)a * nr + (r0 + tx + 16 * j)] = acc[i][j].x + acc[i][j].y + b2v;
        }
    }
}

extern "C" void kernel_launch(void* const* d_in, const int* in_sizes, int n_in,
                              void* d_out, int out_size, void* d_ws, size_t ws_size,
                              hipStream_t stream) {
    const float* xA  = (const float*)d_in[0];
    const float* xR  = (const float*)d_in[1];
    const float* Wa1 = (const float*)d_in[2];
    const float* ba1 = (const float*)d_in[3];
    const float* Wa2 = (const float*)d_in[4];
    const float* ba2 = (const float*)d_in[5];
    const float* Wr1 = (const float*)d_in[6];
    const float* br1 = (const float*)d_in[7];
    const float* Wr2 = (const float*)d_in[8];
    const float* br2 = (const float*)d_in[9];
    const float* Ws1 = (const float*)d_in[10];
    const float* bs1 = (const float*)d_in[11];
    const float* Ws2 = (const float*)d_in[12];
    const float* bs2 = (const float*)d_in[13];
    float* out = (float*)d_out;

    const int na = in_sizes[0] / 24;   // 1024
    const int nr = in_sizes[1] / 20;   // 1024

    float* pa = (float*)d_ws;                       // na*128 floats (bs1 folded in)
    float* pr = pa + (size_t)na * H;                // nr*128 floats

    emb_kernel<<<dim3(na / 8 + nr / 8), 256, 0, stream>>>(
        xA, xR, Wa1, ba1, Wa2, ba2, Wr1, br1, Wr2, br2, Ws1, bs1, pa, pr, na, nr);

    pair_kernel<<<dim3(nr / 32, na / 64), 256, 0, stream>>>(
        pa, pr, Ws2, bs2, out, nr);
}